// Round 2
// baseline (327.001 us; speedup 1.0000x reference)
//
#include <hip/hip_runtime.h>
#include <stdint.h>

#define AS1 __attribute__((address_space(1)))
#define AS3 __attribute__((address_space(3)))

typedef __bf16 bf16x8 __attribute__((ext_vector_type(8)));
typedef float f32x4 __attribute__((ext_vector_type(4)));
typedef float f32x16 __attribute__((ext_vector_type(16)));

__device__ __forceinline__ unsigned short f2bf(float f) {
  unsigned u = __float_as_uint(f);
  u += 0x7FFF + ((u >> 16) & 1);   // round-to-nearest-even
  return (unsigned short)(u >> 16);
}
__device__ __forceinline__ float bf2f(unsigned short h) {
  return __uint_as_float(((unsigned)h) << 16);
}

// ---------------- fp32 -> bf16 cast, 4 elems/thread ----------------
__global__ __launch_bounds__(256) void cast_kernel(const float* __restrict__ in,
                                                   unsigned short* __restrict__ out,
                                                   int n4) {
  int i = blockIdx.x * 256 + threadIdx.x;
  if (i >= n4) return;
  float4 v = reinterpret_cast<const float4*>(in)[i];
  ushort4 o;
  o.x = f2bf(v.x); o.y = f2bf(v.y); o.z = f2bf(v.z); o.w = f2bf(v.w);
  reinterpret_cast<ushort4*>(out)[i] = o;
}

// ---------------- GEMM-BT: C[m][n] = sum_k A[m][k]*B[n][k] (+bias[n]) ----------------
// A,B bf16, K-contiguous rows. 128x128 block tile, BK=32, 4 waves (2x2 of 64x64),
// each wave 2x2 MFMA 32x32x16 tiles. global_load_lds width-16 staging.
// LDS rows are 64 B; 16 B chunk index XOR-swizzled by ((row>>1)&3) to spread
// fragment reads across all eight 4-bank groups (kills the 6.3M conflict cycles
// measured in R0). Staging sources the permuted global chunk so the LDS dst
// stays lane-contiguous (global_load_lds requirement).
template<int OUT_BF16>
__global__ __launch_bounds__(256, 2) void gemm_bt(
    const unsigned short* __restrict__ A, long lda, long strideA,
    const unsigned short* __restrict__ B, long ldb, long strideB,
    void* __restrict__ Cv, long ldc, long strideC,
    const float* __restrict__ bias, int K) {
  __shared__ unsigned short sA[128 * 32];
  __shared__ unsigned short sB[128 * 32];
  const int t = threadIdx.x;
  const int lane = t & 63;
  const int wave = t >> 6;

  const unsigned short* Ab = A + (size_t)blockIdx.z * strideA + (size_t)blockIdx.y * 128 * lda;
  const unsigned short* Bb = B + (size_t)blockIdx.z * strideB + (size_t)blockIdx.x * 128 * ldb;

  // staging: thread t -> row t>>2 (0..63), swizzled 16B chunk; two halves of 64 rows
  const int srow = t >> 2;
  const int schunk = (t & 3) ^ ((srow >> 1) & 3);   // XOR swizzle source chunk
  const unsigned short* aptr = Ab + (size_t)srow * lda + schunk * 8;
  const unsigned short* bptr = Bb + (size_t)srow * ldb + schunk * 8;
  char* ldsA0 = (char*)&sA[0] + wave * 1024;  // wave-uniform LDS base (+ lane*16 implicit)
  char* ldsB0 = (char*)&sB[0] + wave * 1024;

  f32x16 acc[2][2];
#pragma unroll
  for (int i = 0; i < 2; i++)
#pragma unroll
    for (int j = 0; j < 2; j++)
#pragma unroll
      for (int r = 0; r < 16; r++) acc[i][j][r] = 0.f;

  const int wm = (wave >> 1) * 64;
  const int wn = (wave & 1) * 64;
  const int r31 = lane & 31;
  const int half = lane >> 5;            // k-half within 16
  const int swz = (r31 >> 1) & 3;        // row-dependent chunk swizzle (lane-only)

  // Precompute LDS byte offsets: tile i (m or n), k-step s. Row = base+i*32+r31,
  // chunk = (2*s + half) ^ swz. sA row stride = 64 B.
  int offA[2][2], offB[2][2];
#pragma unroll
  for (int i = 0; i < 2; i++)
#pragma unroll
    for (int s = 0; s < 2; s++) {
      offA[i][s] = (wm + i * 32 + r31) * 64 + (((2 * s + half) ^ swz) * 16);
      offB[i][s] = (wn + i * 32 + r31) * 64 + (((2 * s + half) ^ swz) * 16);
    }

  for (int k0 = 0; k0 < K; k0 += 32) {
    __syncthreads();
    __builtin_amdgcn_global_load_lds((AS1 void*)(aptr + k0), (AS3 void*)ldsA0, 16, 0, 0);
    __builtin_amdgcn_global_load_lds((AS1 void*)(aptr + 64 * lda + k0), (AS3 void*)(ldsA0 + 4096), 16, 0, 0);
    __builtin_amdgcn_global_load_lds((AS1 void*)(bptr + k0), (AS3 void*)ldsB0, 16, 0, 0);
    __builtin_amdgcn_global_load_lds((AS1 void*)(bptr + 64 * ldb + k0), (AS3 void*)(ldsB0 + 4096), 16, 0, 0);
    __syncthreads();
#pragma unroll
    for (int s = 0; s < 2; s++) {
      bf16x8 af[2], bfv[2];
#pragma unroll
      for (int i = 0; i < 2; i++) {
        af[i]  = *reinterpret_cast<const bf16x8*>((const char*)sA + offA[i][s]);
        bfv[i] = *reinterpret_cast<const bf16x8*>((const char*)sB + offB[i][s]);
      }
#pragma unroll
      for (int i = 0; i < 2; i++)
#pragma unroll
        for (int j = 0; j < 2; j++)
          acc[i][j] = __builtin_amdgcn_mfma_f32_32x32x16_bf16(af[i], bfv[j], acc[i][j], 0, 0, 0);
    }
  }

  // epilogue: 32x32 C/D layout col=lane&31, row=(reg&3)+8*(reg>>2)+4*(lane>>5)
#pragma unroll
  for (int i = 0; i < 2; i++) {
    int gmb = blockIdx.y * 128 + wm + i * 32;
#pragma unroll
    for (int j = 0; j < 2; j++) {
      int gn = blockIdx.x * 128 + wn + j * 32 + r31;
      float bv = bias ? bias[gn] : 0.0f;
#pragma unroll
      for (int r = 0; r < 16; r++) {
        int row = (r & 3) + 8 * (r >> 2) + 4 * half;
        float val = acc[i][j][r] + bv;
        size_t off = (size_t)blockIdx.z * strideC + (size_t)(gmb + row) * ldc + gn;
        if (OUT_BF16)
          ((unsigned short*)Cv)[off] = f2bf(val);
        else
          ((float*)Cv)[off] = val;
      }
    }
  }
}

// ---------------- transpose V[b][s][d] -> Vt[b][d][s], bf16 ----------------
__global__ __launch_bounds__(256) void transpose_v(const unsigned short* __restrict__ qkv,
                                                   unsigned short* __restrict__ vt) {
  __shared__ unsigned short tile[64][68];
  int t = threadIdx.x;
  int s0 = blockIdx.x * 64, d0 = blockIdx.y * 64, b = blockIdx.z;
  const unsigned short* V = qkv + (size_t)b * 2048 * 3072 + 2048;
  unsigned short* Vt = vt + (size_t)b * 1024 * 2048;
  int r = t >> 4, c = (t & 15) * 4;
#pragma unroll
  for (int i = 0; i < 4; i++) {
    int s = r + i * 16;
    ushort4 v4 = *reinterpret_cast<const ushort4*>(&V[(size_t)(s0 + s) * 3072 + d0 + c]);
    tile[s][c] = v4.x; tile[s][c + 1] = v4.y; tile[s][c + 2] = v4.z; tile[s][c + 3] = v4.w;
  }
  __syncthreads();
#pragma unroll
  for (int i = 0; i < 4; i++) {
    int d = r + i * 16;
    ushort4 o;
    o.x = tile[c][d]; o.y = tile[c + 1][d]; o.z = tile[c + 2][d]; o.w = tile[c + 3][d];
    *reinterpret_cast<ushort4*>(&Vt[(size_t)(d0 + d) * 2048 + s0 + c]) = o;
  }
}

// ---------------- in-place row softmax over bf16 scores ----------------
// ref: scores = where(mask==0, -1e20, scores); softmax(scores / sqrt(1024))
__global__ __launch_bounds__(256) void softmax_kernel(unsigned short* __restrict__ P,
                                                      const int* __restrict__ mask) {
  __shared__ float red[8];
  const int S = 2048;
  int row = blockIdx.x;
  int b = row >> 11;
  unsigned short* prow = P + (size_t)row * S;
  const int* mrow = mask + (size_t)b * S;
  int t = threadIdx.x;
  int base = t * 8;
  uint4 raw = *reinterpret_cast<const uint4*>(&prow[base]);
  int4 m0 = *reinterpret_cast<const int4*>(&mrow[base]);
  int4 m1 = *reinterpret_cast<const int4*>(&mrow[base + 4]);
  unsigned short us[8];
  us[0] = raw.x & 0xffff; us[1] = raw.x >> 16;
  us[2] = raw.y & 0xffff; us[3] = raw.y >> 16;
  us[4] = raw.z & 0xffff; us[5] = raw.z >> 16;
  us[6] = raw.w & 0xffff; us[7] = raw.w >> 16;
  int mk[8] = {m0.x, m0.y, m0.z, m0.w, m1.x, m1.y, m1.z, m1.w};
  float l[8];
  float mx = -3.4e38f;
#pragma unroll
  for (int j = 0; j < 8; j++) {
    float v = bf2f(us[j]);
    v = (mk[j] == 0) ? -1e20f : v;   // mask BEFORE scaling, per reference
    l[j] = v * 0.03125f;             // 1/sqrt(1024)
    mx = fmaxf(mx, l[j]);
  }
#pragma unroll
  for (int o = 32; o >= 1; o >>= 1) mx = fmaxf(mx, __shfl_xor(mx, o, 64));
  if ((t & 63) == 0) red[t >> 6] = mx;
  __syncthreads();
  mx = fmaxf(fmaxf(red[0], red[1]), fmaxf(red[2], red[3]));
  float e[8], s = 0.f;
#pragma unroll
  for (int j = 0; j < 8; j++) { e[j] = __expf(l[j] - mx); s += e[j]; }
#pragma unroll
  for (int o = 32; o >= 1; o >>= 1) s += __shfl_xor(s, o, 64);
  if ((t & 63) == 0) red[4 + (t >> 6)] = s;
  __syncthreads();
  s = red[4] + red[5] + red[6] + red[7];
  float inv = 1.0f / s;
  unsigned short eo[8];
#pragma unroll
  for (int j = 0; j < 8; j++) eo[j] = f2bf(e[j] * inv);
  uint4 outv;
  outv.x = eo[0] | ((unsigned)eo[1] << 16);
  outv.y = eo[2] | ((unsigned)eo[3] << 16);
  outv.z = eo[4] | ((unsigned)eo[5] << 16);
  outv.w = eo[6] | ((unsigned)eo[7] << 16);
  *reinterpret_cast<uint4*>(&prow[base]) = outv;
}

extern "C" void kernel_launch(void* const* d_in, const int* in_sizes, int n_in,
                              void* d_out, int out_size, void* d_ws, size_t ws_size,
                              hipStream_t stream) {
  const float* X = (const float*)d_in[0];
  const int* mask = (const int*)d_in[1];
  const float* W_in = (const float*)d_in[2];
  const float* b_in = (const float*)d_in[3];
  const float* W_out = (const float*)d_in[4];
  const float* b_out = (const float*)d_in[5];
  float* out = (float*)d_out;

  const int S = 2048, D = 1024;  // B=4 fixed below via grids
  // workspace layout (bytes):
  //   Xb  [8192x1024] bf16  16777216   (reused as Ob after GEMM1)
  //   Wib [3072x1024] bf16   6291456
  //   Wob [1024x1024] bf16   2097152
  //   QKV [8192x3072] bf16  50331648
  //   P   [4x2048x2048] bf16 33554432  (scores, softmaxed in place)
  //   Vt  [4x1024x2048] bf16 16777216   -> total 125829120
  char* w = (char*)d_ws;
  unsigned short* Xb  = (unsigned short*)w;
  unsigned short* Wib = (unsigned short*)(w + 16777216);
  unsigned short* Wob = (unsigned short*)(w + 16777216 + 6291456);
  unsigned short* QKV = (unsigned short*)(w + 16777216 + 6291456 + 2097152);
  unsigned short* P   = (unsigned short*)(w + 16777216 + 6291456 + 2097152 + 50331648);
  unsigned short* Vt  = (unsigned short*)(w + 16777216 + 6291456 + 2097152 + 50331648 + 33554432);
  unsigned short* Ob  = Xb;

  cast_kernel<<<8192, 256, 0, stream>>>(X, Xb, 2097152);
  cast_kernel<<<3072, 256, 0, stream>>>(W_in, Wib, 786432);
  cast_kernel<<<1024, 256, 0, stream>>>(W_out, Wob, 262144);

  // QKV = Xb @ W_in^T + b_in   [8192 x 3072] bf16
  gemm_bt<1><<<dim3(24, 64, 1), 256, 0, stream>>>(Xb, D, 0, Wib, D, 0,
                                                  QKV, 3 * D, 0, b_in, D);
  // Vt[b][d][s] = V[b][s][d]
  transpose_v<<<dim3(32, 16, 4), 256, 0, stream>>>(QKV, Vt);
  // scores[b] = Q[b] @ K[b]^T  [2048 x 2048] bf16 (raw, mask/scale in softmax)
  gemm_bt<1><<<dim3(16, 16, 4), 256, 0, stream>>>(QKV, 3 * D, (long)S * 3 * D,
                                                  QKV + D, 3 * D, (long)S * 3 * D,
                                                  P, S, (long)S * S, nullptr, D);
  softmax_kernel<<<8192, 256, 0, stream>>>(P, mask);
  // O[b] = P[b] @ Vt[b]^T      [2048 x 1024] bf16
  gemm_bt<1><<<dim3(8, 16, 4), 256, 0, stream>>>(P, S, (long)S * S,
                                                 Vt, S, (long)D * S,
                                                 Ob, D, (long)S * D, nullptr, S);
  // out = O @ W_out^T + b_out  [8192 x 1024] fp32
  gemm_bt<0><<<dim3(8, 64, 1), 256, 0, stream>>>(Ob, D, 0, Wob, D, 0,
                                                 out, D, 0, b_out, D);
}

// Round 3
// 302.138 us; speedup vs baseline: 1.0823x; 1.0823x over previous
//
#include <hip/hip_runtime.h>
#include <stdint.h>

#define AS1 __attribute__((address_space(1)))
#define AS3 __attribute__((address_space(3)))

typedef __bf16 bf16x8 __attribute__((ext_vector_type(8)));
typedef float f32x16 __attribute__((ext_vector_type(16)));

__device__ __forceinline__ unsigned short f2bf(float f) {
  unsigned u = __float_as_uint(f);
  u += 0x7FFF + ((u >> 16) & 1);   // round-to-nearest-even
  return (unsigned short)(u >> 16);
}
__device__ __forceinline__ float bf2f(unsigned short h) {
  return __uint_as_float(((unsigned)h) << 16);
}

// ---------------- fp32 -> bf16 cast, 4 elems/thread ----------------
__global__ __launch_bounds__(256) void cast_kernel(const float* __restrict__ in,
                                                   unsigned short* __restrict__ out,
                                                   int n4) {
  int i = blockIdx.x * 256 + threadIdx.x;
  if (i >= n4) return;
  float4 v = reinterpret_cast<const float4*>(in)[i];
  ushort4 o;
  o.x = f2bf(v.x); o.y = f2bf(v.y); o.z = f2bf(v.z); o.w = f2bf(v.w);
  reinterpret_cast<ushort4*>(out)[i] = o;
}

// ---------------- GEMM-BT: C[m][n] = sum_k A[m][k]*B[n][k] (+bias[n]) ----------------
// A,B bf16, K-contiguous rows. 128x128 block tile, BK=64 (halves barrier count vs
// BK=32 — R2 showed MFMA pipe idle 73%, barrier-drain limited). 4 waves, each a
// 64x64 tile of 2x2 32x32x16 MFMA; 4 k-steps (16 MFMA) per barrier pair.
// LDS rows are 128 B; 16 B chunks XOR-swizzled by (row&7) so fragment reads
// spread over all 8 bank groups. Staging sources the permuted global chunk so
// the global_load_lds LDS dst stays lane-contiguous.
template<int OUT_BF16>
__global__ __launch_bounds__(256, 2) void gemm_bt(
    const unsigned short* __restrict__ A, long lda, long strideA,
    const unsigned short* __restrict__ B, long ldb, long strideB,
    void* __restrict__ Cv, long ldc, long strideC,
    const float* __restrict__ bias, int K) {
  __shared__ unsigned short sA[128 * 64];
  __shared__ unsigned short sB[128 * 64];
  const int t = threadIdx.x;
  const int lane = t & 63;
  const int wave = t >> 6;

  const unsigned short* Ab = A + (size_t)blockIdx.z * strideA + (size_t)blockIdx.y * 128 * lda;
  const unsigned short* Bb = B + (size_t)blockIdx.z * strideB + (size_t)blockIdx.x * 128 * ldb;

  // staging: 4 ops per matrix per iter; op o covers rows o*32..o*32+31.
  // thread t -> row (t>>3), swizzled source chunk (t&7)^((t>>3)&7).
  const int srow = t >> 3;
  const int schunk = (t & 7) ^ (srow & 7);
  const unsigned short* aptr = Ab + (size_t)srow * lda + schunk * 8;
  const unsigned short* bptr = Bb + (size_t)srow * ldb + schunk * 8;
  char* ldsA0 = (char*)&sA[0] + wave * 1024;  // + lane*16 implicit per op
  char* ldsB0 = (char*)&sB[0] + wave * 1024;

  f32x16 acc[2][2];
#pragma unroll
  for (int i = 0; i < 2; i++)
#pragma unroll
    for (int j = 0; j < 2; j++)
#pragma unroll
      for (int r = 0; r < 16; r++) acc[i][j][r] = 0.f;

  const int wm = (wave >> 1) * 64;
  const int wn = (wave & 1) * 64;
  const int r31 = lane & 31;
  const int half = lane >> 5;            // k-half within 16
  const int swz = r31 & 7;               // row-dependent chunk swizzle (lane-only)

  // LDS byte offsets: row = wbase + i*32 + r31 (stride 128B),
  // logical chunk (2s+half) stored at physical chunk (2s+half)^swz.
  int offA[2][4], offB[2][4];
#pragma unroll
  for (int i = 0; i < 2; i++)
#pragma unroll
    for (int s = 0; s < 4; s++) {
      offA[i][s] = (wm + i * 32 + r31) * 128 + (((2 * s + half) ^ swz) * 16);
      offB[i][s] = (wn + i * 32 + r31) * 128 + (((2 * s + half) ^ swz) * 16);
    }

  for (int k0 = 0; k0 < K; k0 += 64) {
    __syncthreads();
#pragma unroll
    for (int o = 0; o < 4; o++) {
      __builtin_amdgcn_global_load_lds((AS1 void*)(aptr + (size_t)o * 32 * lda + k0),
                                       (AS3 void*)(ldsA0 + o * 4096), 16, 0, 0);
      __builtin_amdgcn_global_load_lds((AS1 void*)(bptr + (size_t)o * 32 * ldb + k0),
                                       (AS3 void*)(ldsB0 + o * 4096), 16, 0, 0);
    }
    __syncthreads();
#pragma unroll
    for (int s = 0; s < 4; s++) {
      bf16x8 af[2], bfv[2];
#pragma unroll
      for (int i = 0; i < 2; i++) {
        af[i]  = *reinterpret_cast<const bf16x8*>((const char*)sA + offA[i][s]);
        bfv[i] = *reinterpret_cast<const bf16x8*>((const char*)sB + offB[i][s]);
      }
#pragma unroll
      for (int i = 0; i < 2; i++)
#pragma unroll
        for (int j = 0; j < 2; j++)
          acc[i][j] = __builtin_amdgcn_mfma_f32_32x32x16_bf16(af[i], bfv[j], acc[i][j], 0, 0, 0);
    }
  }

  // epilogue: 32x32 C/D layout col=lane&31, row=(reg&3)+8*(reg>>2)+4*(lane>>5)
#pragma unroll
  for (int i = 0; i < 2; i++) {
    int gmb = blockIdx.y * 128 + wm + i * 32;
#pragma unroll
    for (int j = 0; j < 2; j++) {
      int gn = blockIdx.x * 128 + wn + j * 32 + r31;
      float bv = bias ? bias[gn] : 0.0f;
#pragma unroll
      for (int r = 0; r < 16; r++) {
        int row = (r & 3) + 8 * (r >> 2) + 4 * half;
        float val = acc[i][j][r] + bv;
        size_t off = (size_t)blockIdx.z * strideC + (size_t)(gmb + row) * ldc + gn;
        if (OUT_BF16)
          ((unsigned short*)Cv)[off] = f2bf(val);
        else
          ((float*)Cv)[off] = val;
      }
    }
  }
}

// ---------------- transpose V[b][s][d] -> Vt[b][d][s], bf16 ----------------
__global__ __launch_bounds__(256) void transpose_v(const unsigned short* __restrict__ qkv,
                                                   unsigned short* __restrict__ vt) {
  __shared__ unsigned short tile[64][68];
  int t = threadIdx.x;
  int s0 = blockIdx.x * 64, d0 = blockIdx.y * 64, b = blockIdx.z;
  const unsigned short* V = qkv + (size_t)b * 2048 * 3072 + 2048;
  unsigned short* Vt = vt + (size_t)b * 1024 * 2048;
  int r = t >> 4, c = (t & 15) * 4;
#pragma unroll
  for (int i = 0; i < 4; i++) {
    int s = r + i * 16;
    ushort4 v4 = *reinterpret_cast<const ushort4*>(&V[(size_t)(s0 + s) * 3072 + d0 + c]);
    tile[s][c] = v4.x; tile[s][c + 1] = v4.y; tile[s][c + 2] = v4.z; tile[s][c + 3] = v4.w;
  }
  __syncthreads();
#pragma unroll
  for (int i = 0; i < 4; i++) {
    int d = r + i * 16;
    ushort4 o;
    o.x = tile[c][d]; o.y = tile[c + 1][d]; o.z = tile[c + 2][d]; o.w = tile[c + 3][d];
    *reinterpret_cast<ushort4*>(&Vt[(size_t)(d0 + d) * 2048 + s0 + c]) = o;
  }
}

// ---------------- in-place row softmax over bf16 scores ----------------
// ref: scores = where(mask==0, -1e20, scores); softmax(scores / sqrt(1024))
__global__ __launch_bounds__(256) void softmax_kernel(unsigned short* __restrict__ P,
                                                      const int* __restrict__ mask) {
  __shared__ float red[8];
  const int S = 2048;
  int row = blockIdx.x;
  int b = row >> 11;
  unsigned short* prow = P + (size_t)row * S;
  const int* mrow = mask + (size_t)b * S;
  int t = threadIdx.x;
  int base = t * 8;
  uint4 raw = *reinterpret_cast<const uint4*>(&prow[base]);
  int4 m0 = *reinterpret_cast<const int4*>(&mrow[base]);
  int4 m1 = *reinterpret_cast<const int4*>(&mrow[base + 4]);
  unsigned short us[8];
  us[0] = raw.x & 0xffff; us[1] = raw.x >> 16;
  us[2] = raw.y & 0xffff; us[3] = raw.y >> 16;
  us[4] = raw.z & 0xffff; us[5] = raw.z >> 16;
  us[6] = raw.w & 0xffff; us[7] = raw.w >> 16;
  int mk[8] = {m0.x, m0.y, m0.z, m0.w, m1.x, m1.y, m1.z, m1.w};
  float l[8];
  float mx = -3.4e38f;
#pragma unroll
  for (int j = 0; j < 8; j++) {
    float v = bf2f(us[j]);
    v = (mk[j] == 0) ? -1e20f : v;   // mask BEFORE scaling, per reference
    l[j] = v * 0.03125f;             // 1/sqrt(1024)
    mx = fmaxf(mx, l[j]);
  }
#pragma unroll
  for (int o = 32; o >= 1; o >>= 1) mx = fmaxf(mx, __shfl_xor(mx, o, 64));
  if ((t & 63) == 0) red[t >> 6] = mx;
  __syncthreads();
  mx = fmaxf(fmaxf(red[0], red[1]), fmaxf(red[2], red[3]));
  float e[8], s = 0.f;
#pragma unroll
  for (int j = 0; j < 8; j++) { e[j] = __expf(l[j] - mx); s += e[j]; }
#pragma unroll
  for (int o = 32; o >= 1; o >>= 1) s += __shfl_xor(s, o, 64);
  if ((t & 63) == 0) red[4 + (t >> 6)] = s;
  __syncthreads();
  s = red[4] + red[5] + red[6] + red[7];
  float inv = 1.0f / s;
  unsigned short eo[8];
#pragma unroll
  for (int j = 0; j < 8; j++) eo[j] = f2bf(e[j] * inv);
  uint4 outv;
  outv.x = eo[0] | ((unsigned)eo[1] << 16);
  outv.y = eo[2] | ((unsigned)eo[3] << 16);
  outv.z = eo[4] | ((unsigned)eo[5] << 16);
  outv.w = eo[6] | ((unsigned)eo[7] << 16);
  *reinterpret_cast<uint4*>(&prow[base]) = outv;
}

extern "C" void kernel_launch(void* const* d_in, const int* in_sizes, int n_in,
                              void* d_out, int out_size, void* d_ws, size_t ws_size,
                              hipStream_t stream) {
  const float* X = (const float*)d_in[0];
  const int* mask = (const int*)d_in[1];
  const float* W_in = (const float*)d_in[2];
  const float* b_in = (const float*)d_in[3];
  const float* W_out = (const float*)d_in[4];
  const float* b_out = (const float*)d_in[5];
  float* out = (float*)d_out;

  const int S = 2048, D = 1024;  // B=4 fixed below via grids
  // workspace layout (bytes):
  //   Xb  [8192x1024] bf16  16777216   (reused as Ob after GEMM1)
  //   Wib [3072x1024] bf16   6291456
  //   Wob [1024x1024] bf16   2097152
  //   QKV [8192x3072] bf16  50331648
  //   P   [4x2048x2048] bf16 33554432  (scores, softmaxed in place)
  //   Vt  [4x1024x2048] bf16 16777216   -> total 125829120
  char* w = (char*)d_ws;
  unsigned short* Xb  = (unsigned short*)w;
  unsigned short* Wib = (unsigned short*)(w + 16777216);
  unsigned short* Wob = (unsigned short*)(w + 16777216 + 6291456);
  unsigned short* QKV = (unsigned short*)(w + 16777216 + 6291456 + 2097152);
  unsigned short* P   = (unsigned short*)(w + 16777216 + 6291456 + 2097152 + 50331648);
  unsigned short* Vt  = (unsigned short*)(w + 16777216 + 6291456 + 2097152 + 50331648 + 33554432);
  unsigned short* Ob  = Xb;

  cast_kernel<<<8192, 256, 0, stream>>>(X, Xb, 2097152);
  cast_kernel<<<3072, 256, 0, stream>>>(W_in, Wib, 786432);
  cast_kernel<<<1024, 256, 0, stream>>>(W_out, Wob, 262144);

  // QKV = Xb @ W_in^T + b_in   [8192 x 3072] bf16
  gemm_bt<1><<<dim3(24, 64, 1), 256, 0, stream>>>(Xb, D, 0, Wib, D, 0,
                                                  QKV, 3 * D, 0, b_in, D);
  // Vt[b][d][s] = V[b][s][d]
  transpose_v<<<dim3(32, 16, 4), 256, 0, stream>>>(QKV, Vt);
  // scores[b] = Q[b] @ K[b]^T  [2048 x 2048] bf16 (raw, mask/scale in softmax)
  gemm_bt<1><<<dim3(16, 16, 4), 256, 0, stream>>>(QKV, 3 * D, (long)S * 3 * D,
                                                  QKV + D, 3 * D, (long)S * 3 * D,
                                                  P, S, (long)S * S, nullptr, D);
  softmax_kernel<<<8192, 256, 0, stream>>>(P, mask);
  // O[b] = P[b] @ Vt[b]^T      [2048 x 1024] bf16
  gemm_bt<1><<<dim3(8, 16, 4), 256, 0, stream>>>(P, S, (long)S * S,
                                                 Vt, S, (long)D * S,
                                                 Ob, D, (long)S * D, nullptr, S);
  // out = O @ W_out^T + b_out  [8192 x 1024] fp32
  gemm_bt<0><<<dim3(8, 64, 1), 256, 0, stream>>>(Ob, D, 0, Wob, D, 0,
                                                 out, D, 0, b_out, D);
}